// Round 6
// baseline (97.635 us; speedup 1.0000x reference)
//
#include <hip/hip_runtime.h>
#include <hip/hip_bf16.h>
#include <math.h>

#define BS   8
#define NPTS 2048
#define CCH  12      // channels per flow
#define NF   2       // flow dim
#define DIM  24      // NF*CCH, feats order: d = f*12 + c
#define KPAD 32      // MFMA K (24 + 8 zero pad)
#define KTOP 16
#define NWV  8       // waves per fused block (512 threads)
#define RPB  16      // rows per block (one m-tile)
#define CBUF 176     // survivor slots per row (~45 expected, >10 sigma headroom)
#define CBS  177     // padded stride

#define NROWS    (BS * NPTS)
#define TGT_BASE (NROWS * KTOP * CCH)   // 3145728

// hi-only bf16 mfma approx (<= 7.9e-3) + mn-side slop (7.9e-3) + bf16
// truncation of retained dots (<= 3.9e-3, one-sided toward zero)
// -> need >= 0.0197; use 0.024
#define MARGIN 0.024f

typedef unsigned long long u64;
typedef unsigned int       u32;
typedef unsigned short     u16;
typedef __attribute__((ext_vector_type(8))) short short8;   // bf16x8 MFMA frag
typedef __attribute__((ext_vector_type(4))) float f32x4;

// ws layout (bytes)
#define WS_FEATS 0                                  // fp32 [NROWS][24]
#define WS_RAW   (NROWS * DIM * 4)                  // fp32 [NROWS][12]
#define WS_FHI   (WS_RAW + NROWS * CCH * 4)         // bf16 [NROWS][32]

// Emulate np.linalg.norm(v) + 1e-8 in float32 exactly (numpy pairwise sum, n=24)
__device__ __forceinline__ float np_norm_den(const float* __restrict__ v)
{
#pragma clang fp contract(off)
    float s[DIM];
    #pragma unroll
    for (int d = 0; d < DIM; ++d) s[d] = v[d] * v[d];
    float r[8];
    #pragma unroll
    for (int j = 0; j < 8; ++j) r[j] = (s[j] + s[j + 8]) + s[j + 16];
    float res = ((r[0] + r[1]) + (r[2] + r[3])) + ((r[4] + r[5]) + (r[6] + r[7]));
    return sqrtf(res) + 1e-8f;
}

// Monotone float -> u32 (preserves total order for finite floats)
__device__ __forceinline__ u32 ordf(float f)
{
    u32 u = __float_as_uint(f);
    return ((int)u >= 0) ? (u | 0x80000000u) : ~u;
}

// round-to-nearest-even fp32 -> bf16 bits (finite inputs)
__device__ __forceinline__ u16 bf16_rne(float x)
{
    u32 bits = __float_as_uint(x);
    bits += 0x7fffu + ((bits >> 16) & 1u);
    return (u16)(bits >> 16);
}

// running top-4 insert (desc t0>=t1>=t2>=t3): 1 max + 3 med3
__device__ __forceinline__ void ins4(float& t0, float& t1, float& t2, float& t3, float v)
{
#if __has_builtin(__builtin_amdgcn_fmed3f)
    const float n0 = fmaxf(t0, v);
    const float n1 = __builtin_amdgcn_fmed3f(t0, t1, v);
    const float n2 = __builtin_amdgcn_fmed3f(t1, t2, v);
    const float n3 = __builtin_amdgcn_fmed3f(t2, t3, v);
#else
    const float n0 = fmaxf(t0, v);
    const float n1 = fmaxf(t1, fminf(t0, v));
    const float n2 = fmaxf(t2, fminf(t1, v));
    const float n3 = fmaxf(t3, fminf(t2, v));
#endif
    t0 = n0; t1 = n1; t2 = n2; t3 = n3;
}

#define CE(a, b) { const float h_ = fmaxf(a, b), l_ = fminf(a, b); a = h_; b = l_; }

// ---------------------------------------------------------------------------
// Kernel 0: normalize rows (numpy-exact fp32); write fp32 feats, bf16 hi
// (K-padded to 32), raw flow slice, and the tgt_out output.
// 256 blocks x 64 thr -> covers 256 CUs (latency-bound kernel).
// ---------------------------------------------------------------------------
__global__ __launch_bounds__(64) void prep_kernel(
    const float* __restrict__ x_c,     // [8][12][2][2048]
    const int*   __restrict__ flow_p,
    float*       __restrict__ feats,   // [NROWS][24] normalized fp32
    u16*         __restrict__ fhi,     // [NROWS][32] bf16 hi
    float*       __restrict__ raw,     // [NROWS][12] raw flow slice
    float*       __restrict__ out)
{
    const int t = blockIdx.x * 64 + threadIdx.x;   // global row
    const int b = t >> 11;
    const int n = t & (NPTS - 1);
    const float* xb = x_c + (size_t)b * CCH * NF * NPTS;

    float v[DIM];
    float fn[DIM];
    {
#pragma clang fp contract(off)
        #pragma unroll
        for (int c = 0; c < CCH; ++c)
            #pragma unroll
            for (int f = 0; f < NF; ++f)
                v[f * CCH + c] = xb[(c * NF + f) * NPTS + n];

        const float den = np_norm_den(v);
        #pragma unroll
        for (int d = 0; d < DIM; ++d) fn[d] = v[d] / den;
    }

    // vectorized feats store: 6 x f32x4
    float* fo = feats + (size_t)t * DIM;
    #pragma unroll
    for (int j = 0; j < 6; ++j)
        *(f32x4*)(fo + 4 * j) = *(f32x4*)(fn + 4 * j);

    // bf16 hi row in regs, store as 4 x short8
    u16 hb[KPAD];
    #pragma unroll
    for (int d = 0; d < DIM; ++d) hb[d] = bf16_rne(fn[d]);
    #pragma unroll
    for (int d = DIM; d < KPAD; ++d) hb[d] = 0;

    u16* ho = fhi + (size_t)t * KPAD;
    #pragma unroll
    for (int j = 0; j < 4; ++j)
        *(short8*)(ho + 8 * j) = ((const short8*)hb)[j];

    const int flow = flow_p[0];
    float rv[CCH];
    #pragma unroll
    for (int c = 0; c < CCH; ++c) {
        rv[c] = flow ? v[CCH + c] : v[c];
        out[TGT_BASE + ((size_t)b * CCH + c) * NPTS + n] = rv[c];
    }
    float* ro = raw + (size_t)t * CCH;
    #pragma unroll
    for (int j = 0; j < 3; ++j)
        *(f32x4*)(ro + 4 * j) = *(f32x4*)(rv + 4 * j);
}

// ---------------------------------------------------------------------------
// Fused kernel: block = (b, 16-row chunk), 512 thr = 8 waves, 1024 blocks.
// R16: swapped MFMA operands (row lane-local); hi-only MFMA; top-4/wave +
//      exact 16th-of-32 threshold.
// R18: pass-1 dots RETAINED in regs and threshold-compared from registers
//      -> pass 2 scans only the second 1024 cands.  vk4 de-aliased from
//      ckey + all-waves-redundant threshold -> 4 barriers, no wave-0
//      serialization.  Depth-3 prefetch.
// R19 FIX: R18's inline-asm v_cvt_pk_bf16_f32 retain was the prime suspect
//      for the absmax-7.3 failure (if its half-packing order is reversed,
//      indices and values decouple and true top-16 get dropped).  Replaced
//      with explicit bit-op TRUNCATION packing (v_lshrrev + v_and_or_b32):
//      pk = (bits(acc1) & 0xffff0000) | (bits(acc0) >> 16).  Deterministic,
//      one-sided error <= 3.9e-3, inside MARGIN's 0.024 budget (0.0197 req).
// Exact rescue (bit-exact fp32 chain) + parallel rank-select + gather.
// ---------------------------------------------------------------------------
__global__ __launch_bounds__(512) void fused_topk_kernel(
    const float* __restrict__ feats,
    const u16*   __restrict__ fhi,
    const float* __restrict__ raw,
    float*       __restrict__ out)
{
    __shared__ f32x4 vk4[NWV * 16];      // 2 KiB: per-wave top-4 lists [w][row16]
    __shared__ u64   ckey[RPB * CBS];    // 22.7 KiB: survivors
    __shared__ int   cnt[RPB];
    __shared__ int   sel[RPB][KTOP];

    const int tid  = threadIdx.x;
    const int lane = tid & 63;
    const int w    = __builtin_amdgcn_readfirstlane(tid >> 6);  // 0..7
    const int b     = blockIdx.x >> 7;
    const int chunk = blockIdx.x & 127;
    const int rb    = chunk * RPB;           // row base within batch
    const int p     = lane & 15;             // our row (C-col with swapped ops)
    const int q     = lane >> 4;             // cand quad (C-row group)

    if (tid < RPB) cnt[tid] = 0;

    // row fragment (B-operand under swap): rows rb+p, k = q*8..q*8+7
    short8 arow;
    {
        const u32 ae = (u32)((b * NPTS + rb + p) * KPAD + q * 8);
        arow = *(const short8*)(fhi + ae);
    }

    // ---- Pass 1: wave w scans cands [w*128, +128), running top-4 per
    //      (row p, cand-slice q); dots retained bf16-truncated in pkv[][].
    float ta0 = -3.0f, ta1 = -3.0f, ta2 = -3.0f, ta3 = -3.0f;
    float tb0 = -3.0f, tb1 = -3.0f, tb2 = -3.0f, tb3 = -3.0f;
    u32 pkv[8][2];
    {
        const u32 base1 = (u32)((b * NPTS + w * 128 + p) * KPAD + q * 8);
        short8 f0 = *(const short8*)(fhi + base1);
        short8 f1 = *(const short8*)(fhi + base1 + 512);
        short8 f2 = *(const short8*)(fhi + base1 + 1024);
        #pragma unroll
        for (int t = 0; t < 8; ++t) {
            const short8 cur = f0;
            f0 = f1; f1 = f2;
            if (t + 3 < 8) f2 = *(const short8*)(fhi + base1 + (u32)(t + 3) * 512);
            f32x4 acc = {0.0f, 0.0f, 0.0f, 0.0f};
            acc = __builtin_amdgcn_mfma_f32_16x16x32_bf16(cur, arow, acc, 0, 0, 0);
            if (t & 1) {
                #pragma unroll
                for (int i = 0; i < 4; ++i) ins4(tb0, tb1, tb2, tb3, acc[i]);
            } else {
                #pragma unroll
                for (int i = 0; i < 4; ++i) ins4(ta0, ta1, ta2, ta3, acc[i]);
            }
            // explicit truncation pack: low16 = acc[even] hi-bits,
            // high16 = acc[odd] hi-bits.  (v_lshrrev + v_and_or_b32)
            pkv[t][0] = (__float_as_uint(acc[1]) & 0xffff0000u) |
                        (__float_as_uint(acc[0]) >> 16);
            pkv[t][1] = (__float_as_uint(acc[3]) & 0xffff0000u) |
                        (__float_as_uint(acc[2]) >> 16);
        }
    }
    // merge the two interleaved lists -> top-4
    float t0 = fmaxf(ta0, tb3), t1 = fmaxf(ta1, tb2), t2 = fmaxf(ta2, tb1), t3 = fmaxf(ta3, tb0);
    CE(t0, t2) CE(t1, t3) CE(t0, t1) CE(t2, t3)

    // ---- unify the 4 q-copies of each row (shfl merges) ----
    #pragma unroll
    for (int x = 16; x <= 32; x <<= 1) {
        const float o0 = __shfl_xor(t0, x), o1 = __shfl_xor(t1, x);
        const float o2 = __shfl_xor(t2, x), o3 = __shfl_xor(t3, x);
        float m0 = fmaxf(t0, o3), m1 = fmaxf(t1, o2), m2 = fmaxf(t2, o1), m3 = fmaxf(t3, o0);
        CE(m0, m2) CE(m1, m3) CE(m0, m1) CE(m2, m3)
        t0 = m0; t1 = m1; t2 = m2; t3 = m3;
    }

    // ---- publish per-wave top-4 per row ----
    if (q == 0) {
        f32x4 v4 = {t0, t1, t2, t3};
        vk4[w * 16 + p] = v4;
    }
    __syncthreads();                         // B1: vk4 + cnt=0 visible

    // ---- ALL waves redundantly compute the exact 16th of the 32 collected
    //      values per row (LDS broadcast reads; result lands in a register).
    float thrp;
    {
        const int j = q;                       // 0..3
        const f32x4 A  = vk4[j * 16 + p];
        const f32x4 Bv = vk4[(j + 4) * 16 + p];
        // merge two sorted-4 desc -> sorted-8 desc
        float s0 = fmaxf(A[0], Bv[3]), s1 = fmaxf(A[1], Bv[2]);
        float s2 = fmaxf(A[2], Bv[1]), s3 = fmaxf(A[3], Bv[0]);
        float s4 = fminf(A[0], Bv[3]), s5 = fminf(A[1], Bv[2]);
        float s6 = fminf(A[2], Bv[1]), s7 = fminf(A[3], Bv[0]);
        CE(s0, s2) CE(s1, s3) CE(s0, s1) CE(s2, s3)
        CE(s4, s6) CE(s5, s7) CE(s4, s5) CE(s6, s7)
        float s[8] = {s0, s1, s2, s3, s4, s5, s6, s7};
        // lane^16 merge: two sorted-8 -> sorted-16 desc
        float t16[16];
        {
            float o[8];
            #pragma unroll
            for (int i = 0; i < 8; ++i) o[i] = __shfl_xor(s[i], 16);
            #pragma unroll
            for (int i = 0; i < 8; ++i) {
                t16[i]     = fmaxf(s[i], o[7 - i]);
                t16[8 + i] = fminf(s[i], o[7 - i]);
            }
            #pragma unroll
            for (int base = 0; base < 16; base += 8) {
                CE(t16[base + 0], t16[base + 4]) CE(t16[base + 1], t16[base + 5])
                CE(t16[base + 2], t16[base + 6]) CE(t16[base + 3], t16[base + 7])
                CE(t16[base + 0], t16[base + 2]) CE(t16[base + 1], t16[base + 3])
                CE(t16[base + 4], t16[base + 6]) CE(t16[base + 5], t16[base + 7])
                CE(t16[base + 0], t16[base + 1]) CE(t16[base + 2], t16[base + 3])
                CE(t16[base + 4], t16[base + 5]) CE(t16[base + 6], t16[base + 7])
            }
        }
        // lane^32 final: 16th of union = min_i max(mine[i], other[15-i])
        float z[16];
        #pragma unroll
        for (int i = 0; i < 16; ++i)
            z[i] = fmaxf(t16[i], __shfl_xor(t16[15 - i], 32));
        float mn = z[0];
        #pragma unroll
        for (int i = 1; i < 16; ++i) mn = fminf(mn, z[i]);
        thrp = mn - MARGIN;
    }

    // ---- Pass 2 prefetch issued FIRST (second 1024 cands), so the L2
    //      latency hides under the retained-register compare below.
    const u32 base2 = (u32)((b * NPTS + 1024 + w * 128 + p) * KPAD + q * 8);
    short8 g0 = *(const short8*)(fhi + base2);
    short8 g1 = *(const short8*)(fhi + base2 + 512);
    short8 g2 = *(const short8*)(fhi + base2 + 1024);

    // ---- retained-register compare+append for the first 1024 cands ----
    #pragma unroll
    for (int t = 0; t < 8; ++t) {
        const int cb0 = w * 128 + t * 16 + q * 4;
        #pragma unroll
        for (int h = 0; h < 2; ++h) {
            const u32 r = pkv[t][h];
            const float v0 = __uint_as_float(r << 16);          // acc[2h]
            const float v1 = __uint_as_float(r & 0xffff0000u);  // acc[2h+1]
            if (v0 >= thrp) {
                const int pos = atomicAdd(&cnt[p], 1);
                if (pos < CBUF) ckey[p * CBS + pos] = (u64)(u32)(cb0 + 2 * h);
            }
            if (v1 >= thrp) {
                const int pos = atomicAdd(&cnt[p], 1);
                if (pos < CBUF) ckey[p * CBS + pos] = (u64)(u32)(cb0 + 2 * h + 1);
            }
        }
    }

    // ---- Pass 2: second 1024 cands (wave w: [1024+w*128,+128)), depth-3 ----
    #pragma unroll
    for (int t = 0; t < 8; ++t) {
        const short8 cur = g0;
        g0 = g1; g1 = g2;
        if (t + 3 < 8) g2 = *(const short8*)(fhi + base2 + (u32)(t + 3) * 512);
        f32x4 acc = {0.0f, 0.0f, 0.0f, 0.0f};
        acc = __builtin_amdgcn_mfma_f32_16x16x32_bf16(cur, arow, acc, 0, 0, 0);
        const int cb0 = 1024 + w * 128 + t * 16 + q * 4;
        #pragma unroll
        for (int i = 0; i < 4; ++i) {
            if (acc[i] >= thrp) {
                const int pos = atomicAdd(&cnt[p], 1);
                if (pos < CBUF) ckey[p * CBS + pos] = (u64)(u32)(cb0 + i);
            }
        }
    }
    __syncthreads();                         // B2: all appends visible

    // ---- exact rescue: bit-exact fp32 chain on survivors only ----
    {
        const int r = tid & 15;                  // row within chunk
        const float* fr = feats + (u32)((b * NPTS + rb + r) * DIM);
        float rfn[DIM];
        #pragma unroll
        for (int j = 0; j < 6; ++j)
            *(f32x4*)(rfn + 4 * j) = *(const f32x4*)(fr + 4 * j);
        const int e = (cnt[r] < CBUF) ? cnt[r] : CBUF;
        for (int pos = tid >> 4; pos < e; pos += 32) {
            const int idx = (int)(u32)ckey[r * CBS + pos];
            const float* cp = feats + (u32)((b * NPTS + idx) * DIM);
            float cv[DIM];
            #pragma unroll
            for (int j = 0; j < 6; ++j)
                *(f32x4*)(cv + 4 * j) = *(const f32x4*)(cp + 4 * j);
            float acc = 0.0f;
            #pragma unroll
            for (int d = 0; d < DIM; ++d)
                acc = __builtin_fmaf(cv[d], rfn[d], acc);   // exact chain
            ckey[r * CBS + pos] = ((u64)ordf(acc) << 32) | (u32)(2047 - idx);
        }
    }
    __syncthreads();                         // B3

    // ---- parallel rank-select: 32 threads per row ----
    {
        const int L = tid >> 5;                  // 0..15
        const int g = tid & 31;
        const int e = (cnt[L] < CBUF) ? cnt[L] : CBUF;
        const u64* rowbuf = &ckey[L * CBS];
        for (int pos = g; pos < e; pos += 32) {
            const u64 key = rowbuf[pos];
            int rank = 0;
            for (int p2 = 0; p2 < e; ++p2) rank += (rowbuf[p2] > key);
            if (rank < KTOP) sel[L][rank] = 2047 - (int)(key & 0xFFFFFFFFull);
        }
    }
    __syncthreads();                         // B4

    // ---- gather: sx_c[b, n, k, c] = raw[(b*2048 + sel)*12 + c] ----
    const int rg = b * NPTS + rb;
    for (int e2 = tid; e2 < RPB * KTOP * CCH; e2 += 512) {
        const int L = e2 / (KTOP * CCH);
        const int r = e2 % (KTOP * CCH);
        const int k = r / CCH;
        const int c = r % CCH;
        out[((size_t)(rg + L) * KTOP + k) * CCH + c] =
            raw[(u32)((b * NPTS + sel[L][k]) * CCH) + c];
    }
}

// ---------------------------------------------------------------------------
extern "C" void kernel_launch(void* const* d_in, const int* in_sizes, int n_in,
                              void* d_out, int out_size, void* d_ws, size_t ws_size,
                              hipStream_t stream)
{
    const float* x_c    = (const float*)d_in[0];
    const int*   flow_p = (const int*)d_in[1];
    float*       out    = (float*)d_out;

    float* feats = (float*)((char*)d_ws + WS_FEATS);
    float* raw   = (float*)((char*)d_ws + WS_RAW);
    u16*   fhi   = (u16*)  ((char*)d_ws + WS_FHI);

    prep_kernel<<<NROWS / 64, 64, 0, stream>>>(x_c, flow_p, feats, fhi, raw, out);
    fused_topk_kernel<<<BS * 128, 512, 0, stream>>>(feats, fhi, raw, out);
}

// Round 7
// 92.605 us; speedup vs baseline: 1.0543x; 1.0543x over previous
//
#include <hip/hip_runtime.h>
#include <hip/hip_bf16.h>
#include <math.h>

#define BS   8
#define NPTS 2048
#define CCH  12      // channels per flow
#define NF   2       // flow dim
#define DIM  24      // NF*CCH, feats order: d = f*12 + c
#define KPAD 32      // MFMA K (24 + 8 zero pad)
#define KTOP 16
#define NWV  8       // waves per fused block (512 threads)
#define RPB  16      // rows per block (one m-tile)
#define CBUF 144     // survivor slots per row (~45 expected @ margin 1.6e-2, >10 sigma)
#define CBS  145     // padded stride

#define NROWS    (BS * NPTS)
#define TGT_BASE (NROWS * KTOP * CCH)   // 3145728

// hi-only bf16 approx: |approx - exact| <= 2*2^-8 + accum ~ 7.9e-3; margin = 2*eps
#define MARGIN 0.016f

typedef unsigned long long u64;
typedef unsigned int       u32;
typedef unsigned short     u16;
typedef __attribute__((ext_vector_type(8))) short short8;   // bf16x8 MFMA frag
typedef __attribute__((ext_vector_type(4))) float f32x4;

// ws layout (bytes)
#define WS_FEATS 0                                  // fp32 [NROWS][24]
#define WS_RAW   (NROWS * DIM * 4)                  // fp32 [NROWS][12]
#define WS_FHI   (WS_RAW + NROWS * CCH * 4)         // bf16 [NROWS][32]

// Emulate np.linalg.norm(v) + 1e-8 in float32 exactly (numpy pairwise sum, n=24)
__device__ __forceinline__ float np_norm_den(const float* __restrict__ v)
{
#pragma clang fp contract(off)
    float s[DIM];
    #pragma unroll
    for (int d = 0; d < DIM; ++d) s[d] = v[d] * v[d];
    float r[8];
    #pragma unroll
    for (int j = 0; j < 8; ++j) r[j] = (s[j] + s[j + 8]) + s[j + 16];
    float res = ((r[0] + r[1]) + (r[2] + r[3])) + ((r[4] + r[5]) + (r[6] + r[7]));
    return sqrtf(res) + 1e-8f;
}

// Monotone float -> u32 (preserves total order for finite floats)
__device__ __forceinline__ u32 ordf(float f)
{
    u32 u = __float_as_uint(f);
    return ((int)u >= 0) ? (u | 0x80000000u) : ~u;
}

// round-to-nearest-even fp32 -> bf16 bits (finite inputs)
__device__ __forceinline__ u16 bf16_rne(float x)
{
    u32 bits = __float_as_uint(x);
    bits += 0x7fffu + ((bits >> 16) & 1u);
    return (u16)(bits >> 16);
}

// running top-4 insert (desc t0>=t1>=t2>=t3): 1 max + 3 med3
__device__ __forceinline__ void ins4(float& t0, float& t1, float& t2, float& t3, float v)
{
#if __has_builtin(__builtin_amdgcn_fmed3f)
    const float n0 = fmaxf(t0, v);
    const float n1 = __builtin_amdgcn_fmed3f(t0, t1, v);
    const float n2 = __builtin_amdgcn_fmed3f(t1, t2, v);
    const float n3 = __builtin_amdgcn_fmed3f(t2, t3, v);
#else
    const float n0 = fmaxf(t0, v);
    const float n1 = fmaxf(t1, fminf(t0, v));
    const float n2 = fmaxf(t2, fminf(t1, v));
    const float n3 = fmaxf(t3, fminf(t2, v));
#endif
    t0 = n0; t1 = n1; t2 = n2; t3 = n3;
}

#define CE(a, b) { const float h_ = fmaxf(a, b), l_ = fminf(a, b); a = h_; b = l_; }

// ---------------------------------------------------------------------------
// Kernel 0: normalize rows (numpy-exact fp32); write fp32 feats, bf16 hi
// (K-padded to 32), raw flow slice, and the tgt_out output.
// 256 blocks x 64 thr -> covers 256 CUs (latency-bound kernel).
// ---------------------------------------------------------------------------
__global__ __launch_bounds__(64) void prep_kernel(
    const float* __restrict__ x_c,     // [8][12][2][2048]
    const int*   __restrict__ flow_p,
    float*       __restrict__ feats,   // [NROWS][24] normalized fp32
    u16*         __restrict__ fhi,     // [NROWS][32] bf16 hi
    float*       __restrict__ raw,     // [NROWS][12] raw flow slice
    float*       __restrict__ out)
{
    const int t = blockIdx.x * 64 + threadIdx.x;   // global row
    const int b = t >> 11;
    const int n = t & (NPTS - 1);
    const float* xb = x_c + (size_t)b * CCH * NF * NPTS;

    float v[DIM];
    float fn[DIM];
    {
#pragma clang fp contract(off)
        #pragma unroll
        for (int c = 0; c < CCH; ++c)
            #pragma unroll
            for (int f = 0; f < NF; ++f)
                v[f * CCH + c] = xb[(c * NF + f) * NPTS + n];

        const float den = np_norm_den(v);
        #pragma unroll
        for (int d = 0; d < DIM; ++d) fn[d] = v[d] / den;
    }

    // vectorized feats store: 6 x f32x4
    float* fo = feats + (size_t)t * DIM;
    #pragma unroll
    for (int j = 0; j < 6; ++j)
        *(f32x4*)(fo + 4 * j) = *(f32x4*)(fn + 4 * j);

    // bf16 hi row in regs, store as 4 x short8
    u16 hb[KPAD];
    #pragma unroll
    for (int d = 0; d < DIM; ++d) hb[d] = bf16_rne(fn[d]);
    #pragma unroll
    for (int d = DIM; d < KPAD; ++d) hb[d] = 0;

    u16* ho = fhi + (size_t)t * KPAD;
    #pragma unroll
    for (int j = 0; j < 4; ++j)
        *(short8*)(ho + 8 * j) = ((const short8*)hb)[j];

    const int flow = flow_p[0];
    float rv[CCH];
    #pragma unroll
    for (int c = 0; c < CCH; ++c) {
        rv[c] = flow ? v[CCH + c] : v[c];
        out[TGT_BASE + ((size_t)b * CCH + c) * NPTS + n] = rv[c];
    }
    float* ro = raw + (size_t)t * CCH;
    #pragma unroll
    for (int j = 0; j < 3; ++j)
        *(f32x4*)(ro + 4 * j) = *(f32x4*)(rv + 4 * j);
}

// ---------------------------------------------------------------------------
// Fused kernel: block = (b, 16-row chunk), 512 thr = 8 waves, 1024 blocks.
// R16: swapped MFMA operands (row lane-local); hi-only MFMA; top-4/wave +
//      exact 16th-of-32 threshold (wave-0 computes).
// R17: u32 incremental tile offsets + depth-2 prefetch (named A/B buffers).
// R20 (this round): FULL REVERT of R18/R19 retained-dots + all-waves-thr
//      (R6 measured +4.5 us: pkv pushed VGPR past the 64-reg 8-wave/SIMD
//      cliff, redundant threshold added VALU to all waves).  New:
//      (a) COHORT STAGGER: co-resident blocks (bid differing by 256) sleep
//          0/~0.9K/~1.8K/~2.7K cyc at entry.  Theory: all blocks launch in
//          lockstep, stall at identical instants -> TLP can't cover
//          (VALUBusy 43% despite 8 waves/SIMD).  Desync lets neighbors fill.
//      (b) pass-2 per-tile early-out (max4 guard skips 4 compare-branches
//          on no-hit tiles, ~24% of tiles).
//      (c) gather loop div-by-192 removed (L = tid>>5 direct).
// Exact rescue (bit-exact fp32 chain) + parallel rank-select + gather.
// ---------------------------------------------------------------------------
__global__ __launch_bounds__(512) void fused_topk_kernel(
    const float* __restrict__ feats,
    const u16*   __restrict__ fhi,
    const float* __restrict__ raw,
    float*       __restrict__ out)
{
    __shared__ union {
        f32x4 vk4[NWV * 16];          // 2 KiB: per-wave top-4 lists [w][row16]
        u64   ckey[RPB * CBS];        // 18.1 KiB: survivors (disjoint in time)
    } sh;
    __shared__ float thr_s[RPB];
    __shared__ int   cnt[RPB];
    __shared__ int   sel[RPB][KTOP];

    const int tid  = threadIdx.x;
    const int lane = tid & 63;
    const int w    = __builtin_amdgcn_readfirstlane(tid >> 6);  // 0..7
    const int b     = blockIdx.x >> 7;
    const int chunk = blockIdx.x & 127;
    const int rb    = chunk * RPB;           // row base within batch
    const int p     = lane & 15;             // our row (C-col with swapped ops)
    const int q     = lane >> 4;             // cand quad (C-row group)

    // R20a: desync the 4 co-resident cohorts (bid mod 256 maps to the same
    // CU; bid>>8 = cohort).  s_sleep frees issue slots (not a spin).
    {
        const int cohort = (int)((blockIdx.x >> 8) & 3);
        for (int s = 0; s < cohort * 2; ++s) __builtin_amdgcn_s_sleep(7);
    }

    if (tid < RPB) cnt[tid] = 0;

    // row fragment (B-operand under swap): rows rb+p, k = q*8..q*8+7
    short8 arow;
    {
        const u32 ae = (u32)((b * NPTS + rb + p) * KPAD + q * 8);
        arow = *(const short8*)(fhi + ae);
    }

    // ---- Pass 1: wave w scans cands [w*128, +128) (8 tiles), running top-4
    //      per (row p, cand-slice q); 2 interleaved lists + depth-2 prefetch.
    float ta0 = -3.0f, ta1 = -3.0f, ta2 = -3.0f, ta3 = -3.0f;
    float tb0 = -3.0f, tb1 = -3.0f, tb2 = -3.0f, tb3 = -3.0f;
    {
        const u32 base1 = (u32)((b * NPTS + w * 128 + p) * KPAD + q * 8);
        short8 pA = *(const short8*)(fhi + base1);          // tile t
        short8 pB = *(const short8*)(fhi + base1 + 512);    // tile t+1
        #pragma unroll
        for (int t = 0; t < 8; t += 2) {
            const short8 c0 = pA;
            if (t + 2 < 8) pA = *(const short8*)(fhi + base1 + (u32)(t + 2) * 512);
            f32x4 acc0 = {0.0f, 0.0f, 0.0f, 0.0f};
            acc0 = __builtin_amdgcn_mfma_f32_16x16x32_bf16(c0, arow, acc0, 0, 0, 0);
            const short8 c1 = pB;
            if (t + 3 < 8) pB = *(const short8*)(fhi + base1 + (u32)(t + 3) * 512);
            f32x4 acc1 = {0.0f, 0.0f, 0.0f, 0.0f};
            acc1 = __builtin_amdgcn_mfma_f32_16x16x32_bf16(c1, arow, acc1, 0, 0, 0);
            #pragma unroll
            for (int i = 0; i < 4; ++i) ins4(ta0, ta1, ta2, ta3, acc0[i]);
            #pragma unroll
            for (int i = 0; i < 4; ++i) ins4(tb0, tb1, tb2, tb3, acc1[i]);
        }
    }
    // merge the two interleaved lists -> top-4 (bitonic: max(a_i, b_{3-i}) + cleanup)
    float t0 = fmaxf(ta0, tb3), t1 = fmaxf(ta1, tb2), t2 = fmaxf(ta2, tb1), t3 = fmaxf(ta3, tb0);
    CE(t0, t2) CE(t1, t3) CE(t0, t1) CE(t2, t3)

    // ---- unify the 4 q-copies of each row (shfl merges) ----
    #pragma unroll
    for (int x = 16; x <= 32; x <<= 1) {
        const float o0 = __shfl_xor(t0, x), o1 = __shfl_xor(t1, x);
        const float o2 = __shfl_xor(t2, x), o3 = __shfl_xor(t3, x);
        float m0 = fmaxf(t0, o3), m1 = fmaxf(t1, o2), m2 = fmaxf(t2, o1), m3 = fmaxf(t3, o0);
        CE(m0, m2) CE(m1, m3) CE(m0, m1) CE(m2, m3)
        t0 = m0; t1 = m1; t2 = m2; t3 = m3;
    }

    // ---- publish per-wave top-4 per row ----
    if (q == 0) {
        f32x4 v4 = {t0, t1, t2, t3};
        sh.vk4[w * 16 + p] = v4;
    }
    __syncthreads();

    // ---- wave 0: exact 16th of the 32 collected values per row ----
    if (w == 0) {
        const int j = q;                       // 0..3
        const f32x4 A  = sh.vk4[j * 16 + p];
        const f32x4 Bv = sh.vk4[(j + 4) * 16 + p];
        // merge two sorted-4 desc -> sorted-8 desc
        float s0 = fmaxf(A[0], Bv[3]), s1 = fmaxf(A[1], Bv[2]);
        float s2 = fmaxf(A[2], Bv[1]), s3 = fmaxf(A[3], Bv[0]);
        float s4 = fminf(A[0], Bv[3]), s5 = fminf(A[1], Bv[2]);
        float s6 = fminf(A[2], Bv[1]), s7 = fminf(A[3], Bv[0]);
        CE(s0, s2) CE(s1, s3) CE(s0, s1) CE(s2, s3)
        CE(s4, s6) CE(s5, s7) CE(s4, s5) CE(s6, s7)
        float s[8] = {s0, s1, s2, s3, s4, s5, s6, s7};
        // j ^ 1 merge: two sorted-8 -> sorted-16 desc
        float t16[16];
        {
            float o[8];
            #pragma unroll
            for (int i = 0; i < 8; ++i) o[i] = __shfl_xor(s[i], 16);
            #pragma unroll
            for (int i = 0; i < 8; ++i) {
                t16[i]     = fmaxf(s[i], o[7 - i]);
                t16[8 + i] = fminf(s[i], o[7 - i]);
            }
            #pragma unroll
            for (int base = 0; base < 16; base += 8) {
                CE(t16[base + 0], t16[base + 4]) CE(t16[base + 1], t16[base + 5])
                CE(t16[base + 2], t16[base + 6]) CE(t16[base + 3], t16[base + 7])
                CE(t16[base + 0], t16[base + 2]) CE(t16[base + 1], t16[base + 3])
                CE(t16[base + 4], t16[base + 6]) CE(t16[base + 5], t16[base + 7])
                CE(t16[base + 0], t16[base + 1]) CE(t16[base + 2], t16[base + 3])
                CE(t16[base + 4], t16[base + 5]) CE(t16[base + 6], t16[base + 7])
            }
        }
        // j ^ 2 final: 16th of union = min_i max(mine[i], other[15-i])
        float z[16];
        #pragma unroll
        for (int i = 0; i < 16; ++i)
            z[i] = fmaxf(t16[i], __shfl_xor(t16[15 - i], 32));
        float mn = z[0];
        #pragma unroll
        for (int i = 1; i < 16; ++i) mn = fminf(mn, z[i]);
        if (q == 0) thr_s[p] = mn - MARGIN;    // lb - 2*eps
    }
    __syncthreads();                 // thr ready; vk4 dead -> ckey usable

    const float thrp = thr_s[p];     // this lane's row threshold

    // ---- Pass 2: all 2048 cands (wave w: [w*256,+256)), depth-2 prefetch ----
    {
        const u32 base2 = (u32)((b * NPTS + w * 256 + p) * KPAD + q * 8);
        short8 pA = *(const short8*)(fhi + base2);
        short8 pB = *(const short8*)(fhi + base2 + 512);
        #pragma unroll
        for (int t = 0; t < 16; t += 2) {
            const short8 c0 = pA;
            if (t + 2 < 16) pA = *(const short8*)(fhi + base2 + (u32)(t + 2) * 512);
            f32x4 acc0 = {0.0f, 0.0f, 0.0f, 0.0f};
            acc0 = __builtin_amdgcn_mfma_f32_16x16x32_bf16(c0, arow, acc0, 0, 0, 0);
            const short8 c1 = pB;
            if (t + 3 < 16) pB = *(const short8*)(fhi + base2 + (u32)(t + 3) * 512);
            f32x4 acc1 = {0.0f, 0.0f, 0.0f, 0.0f};
            acc1 = __builtin_amdgcn_mfma_f32_16x16x32_bf16(c1, arow, acc1, 0, 0, 0);
            const int cb0 = w * 256 + t * 16;
            // R20b: early-out — skip the 4 compare-branches when no value hits
            const float mx0 = fmaxf(fmaxf(acc0[0], acc0[1]), fmaxf(acc0[2], acc0[3]));
            if (mx0 >= thrp) {
                #pragma unroll
                for (int i = 0; i < 4; ++i) {
                    if (acc0[i] >= thrp) {
                        const int pos = atomicAdd(&cnt[p], 1);
                        if (pos < CBUF)
                            sh.ckey[p * CBS + pos] = (u64)(u32)(cb0 + q * 4 + i);
                    }
                }
            }
            const float mx1 = fmaxf(fmaxf(acc1[0], acc1[1]), fmaxf(acc1[2], acc1[3]));
            if (mx1 >= thrp) {
                #pragma unroll
                for (int i = 0; i < 4; ++i) {
                    if (acc1[i] >= thrp) {
                        const int pos = atomicAdd(&cnt[p], 1);
                        if (pos < CBUF)
                            sh.ckey[p * CBS + pos] = (u64)(u32)(cb0 + 16 + q * 4 + i);
                    }
                }
            }
        }
    }
    __syncthreads();

    // ---- exact rescue: bit-exact fp32 chain on survivors only ----
    {
        const int r = tid & 15;                  // row within chunk
        const float* fr = feats + (u32)((b * NPTS + rb + r) * DIM);
        float rfn[DIM];
        #pragma unroll
        for (int j = 0; j < 6; ++j)
            *(f32x4*)(rfn + 4 * j) = *(const f32x4*)(fr + 4 * j);
        const int e = (cnt[r] < CBUF) ? cnt[r] : CBUF;
        for (int pos = tid >> 4; pos < e; pos += 32) {
            const int idx = (int)(u32)sh.ckey[r * CBS + pos];
            const float* cp = feats + (u32)((b * NPTS + idx) * DIM);
            float cv[DIM];
            #pragma unroll
            for (int j = 0; j < 6; ++j)
                *(f32x4*)(cv + 4 * j) = *(const f32x4*)(cp + 4 * j);
            float acc = 0.0f;
            #pragma unroll
            for (int d = 0; d < DIM; ++d)
                acc = __builtin_fmaf(cv[d], rfn[d], acc);   // exact chain
            sh.ckey[r * CBS + pos] = ((u64)ordf(acc) << 32) | (u32)(2047 - idx);
        }
    }
    __syncthreads();

    // ---- parallel rank-select: 32 threads per row ----
    {
        const int L = tid >> 5;                  // 0..15
        const int g = tid & 31;
        const int e = (cnt[L] < CBUF) ? cnt[L] : CBUF;
        const u64* rowbuf = &sh.ckey[L * CBS];
        for (int pos = g; pos < e; pos += 32) {
            const u64 key = rowbuf[pos];
            int rank = 0;
            for (int p2 = 0; p2 < e; ++p2) rank += (rowbuf[p2] > key);
            if (rank < KTOP) sel[L][rank] = 2047 - (int)(key & 0xFFFFFFFFull);
        }
    }
    __syncthreads();

    // ---- gather: sx_c[b, n, k, c] = raw[(b*2048 + sel)*12 + c] ----
    // R20c: div-free row mapping (L = tid>>5, 32 threads/row, 6 elems each)
    {
        const int rg = b * NPTS + rb;
        const int L = tid >> 5;                  // 0..15
        const int g = tid & 31;
        #pragma unroll
        for (int j = 0; j < 6; ++j) {
            const int e3 = g + j * 32;           // 0..191
            const int k = e3 / CCH;
            const int c = e3 - k * CCH;
            out[((size_t)(rg + L) * KTOP + k) * CCH + c] =
                raw[(u32)((b * NPTS + sel[L][k]) * CCH) + c];
        }
    }
}

// ---------------------------------------------------------------------------
extern "C" void kernel_launch(void* const* d_in, const int* in_sizes, int n_in,
                              void* d_out, int out_size, void* d_ws, size_t ws_size,
                              hipStream_t stream)
{
    const float* x_c    = (const float*)d_in[0];
    const int*   flow_p = (const int*)d_in[1];
    float*       out    = (float*)d_out;

    float* feats = (float*)((char*)d_ws + WS_FEATS);
    float* raw   = (float*)((char*)d_ws + WS_RAW);
    u16*   fhi   = (u16*)  ((char*)d_ws + WS_FHI);

    prep_kernel<<<NROWS / 64, 64, 0, stream>>>(x_c, flow_p, feats, fhi, raw, out);
    fused_topk_kernel<<<BS * 128, 512, 0, stream>>>(feats, fhi, raw, out);
}

// Round 8
// 90.007 us; speedup vs baseline: 1.0847x; 1.0289x over previous
//
#include <hip/hip_runtime.h>
#include <hip/hip_bf16.h>
#include <math.h>

#define BS   8
#define NPTS 2048
#define CCH  12      // channels per flow
#define NF   2       // flow dim
#define DIM  24      // NF*CCH, feats order: d = f*12 + c
#define KPAD 32      // MFMA K (24 + 8 zero pad)
#define KTOP 16
#define NWV  8       // waves per fused block (512 threads)
#define RPB  16      // rows per block (one m-tile)
#define CBUF 144     // survivor slots per row (~19 expected @ margin 1.6e-2, huge headroom)
#define CBS  145     // padded stride

#define NROWS    (BS * NPTS)
#define TGT_BASE (NROWS * KTOP * CCH)   // 3145728

// hi-only bf16 approx: |approx - exact| <= 2*2^-8 + accum ~ 7.9e-3; margin = 2*eps
#define MARGIN 0.016f

typedef unsigned long long u64;
typedef unsigned int       u32;
typedef unsigned short     u16;
typedef __attribute__((ext_vector_type(8))) short short8;   // bf16x8 MFMA frag
typedef __attribute__((ext_vector_type(4))) float f32x4;

// ws layout (bytes)
#define WS_FEATS 0                                  // fp32 [NROWS][24]
#define WS_RAW   (NROWS * DIM * 4)                  // fp32 [NROWS][12]
#define WS_FHI   (WS_RAW + NROWS * CCH * 4)         // bf16 [NROWS][32]

// Emulate np.linalg.norm(v) + 1e-8 in float32 exactly (numpy pairwise sum, n=24)
__device__ __forceinline__ float np_norm_den(const float* __restrict__ v)
{
#pragma clang fp contract(off)
    float s[DIM];
    #pragma unroll
    for (int d = 0; d < DIM; ++d) s[d] = v[d] * v[d];
    float r[8];
    #pragma unroll
    for (int j = 0; j < 8; ++j) r[j] = (s[j] + s[j + 8]) + s[j + 16];
    float res = ((r[0] + r[1]) + (r[2] + r[3])) + ((r[4] + r[5]) + (r[6] + r[7]));
    return sqrtf(res) + 1e-8f;
}

// Monotone float -> u32 (preserves total order for finite floats)
__device__ __forceinline__ u32 ordf(float f)
{
    u32 u = __float_as_uint(f);
    return ((int)u >= 0) ? (u | 0x80000000u) : ~u;
}

// round-to-nearest-even fp32 -> bf16 bits (finite inputs)
__device__ __forceinline__ u16 bf16_rne(float x)
{
    u32 bits = __float_as_uint(x);
    bits += 0x7fffu + ((bits >> 16) & 1u);
    return (u16)(bits >> 16);
}

// running top-4 insert (desc t0>=t1>=t2>=t3): 1 max + 3 med3
__device__ __forceinline__ void ins4(float& t0, float& t1, float& t2, float& t3, float v)
{
#if __has_builtin(__builtin_amdgcn_fmed3f)
    const float n0 = fmaxf(t0, v);
    const float n1 = __builtin_amdgcn_fmed3f(t0, t1, v);
    const float n2 = __builtin_amdgcn_fmed3f(t1, t2, v);
    const float n3 = __builtin_amdgcn_fmed3f(t2, t3, v);
#else
    const float n0 = fmaxf(t0, v);
    const float n1 = fmaxf(t1, fminf(t0, v));
    const float n2 = fmaxf(t2, fminf(t1, v));
    const float n3 = fmaxf(t3, fminf(t2, v));
#endif
    t0 = n0; t1 = n1; t2 = n2; t3 = n3;
}

#define CE(a, b) { const float h_ = fmaxf(a, b), l_ = fminf(a, b); a = h_; b = l_; }

// ---------------------------------------------------------------------------
// Kernel 0: normalize rows (numpy-exact fp32); write fp32 feats, bf16 hi
// (K-padded to 32), raw flow slice, and the tgt_out output.
// R21: XCD-pinned indexing — block i handles batch (i&7), row-segment
// (i>>3): all blocks of batch b satisfy blockIdx%8==b -> land on XCD b
// (HW round-robins blockIdx across the 8 XCDs), so writes/reads stay in
// the XCD that will consume them in the fused kernel.
// ---------------------------------------------------------------------------
__global__ __launch_bounds__(64) void prep_kernel(
    const float* __restrict__ x_c,     // [8][12][2][2048]
    const int*   __restrict__ flow_p,
    float*       __restrict__ feats,   // [NROWS][24] normalized fp32
    u16*         __restrict__ fhi,     // [NROWS][32] bf16 hi
    float*       __restrict__ raw,     // [NROWS][12] raw flow slice
    float*       __restrict__ out)
{
    const int b   = (int)(blockIdx.x & 7);          // batch -> XCD b
    const int seg = (int)(blockIdx.x >> 3);         // 0..31
    const int n   = seg * 64 + threadIdx.x;         // row within batch
    const int t   = b * NPTS + n;                   // global row
    const float* xb = x_c + (size_t)b * CCH * NF * NPTS;

    float v[DIM];
    float fn[DIM];
    {
#pragma clang fp contract(off)
        #pragma unroll
        for (int c = 0; c < CCH; ++c)
            #pragma unroll
            for (int f = 0; f < NF; ++f)
                v[f * CCH + c] = xb[(c * NF + f) * NPTS + n];

        const float den = np_norm_den(v);
        #pragma unroll
        for (int d = 0; d < DIM; ++d) fn[d] = v[d] / den;
    }

    // vectorized feats store: 6 x f32x4
    float* fo = feats + (size_t)t * DIM;
    #pragma unroll
    for (int j = 0; j < 6; ++j)
        *(f32x4*)(fo + 4 * j) = *(f32x4*)(fn + 4 * j);

    // bf16 hi row in regs, store as 4 x short8
    u16 hb[KPAD];
    #pragma unroll
    for (int d = 0; d < DIM; ++d) hb[d] = bf16_rne(fn[d]);
    #pragma unroll
    for (int d = DIM; d < KPAD; ++d) hb[d] = 0;

    u16* ho = fhi + (size_t)t * KPAD;
    #pragma unroll
    for (int j = 0; j < 4; ++j)
        *(short8*)(ho + 8 * j) = ((const short8*)hb)[j];

    const int flow = flow_p[0];
    float rv[CCH];
    #pragma unroll
    for (int c = 0; c < CCH; ++c) {
        rv[c] = flow ? v[CCH + c] : v[c];
        out[TGT_BASE + ((size_t)b * CCH + c) * NPTS + n] = rv[c];
    }
    float* ro = raw + (size_t)t * CCH;
    #pragma unroll
    for (int j = 0; j < 3; ++j)
        *(f32x4*)(ro + 4 * j) = *(f32x4*)(rv + 4 * j);
}

// ---------------------------------------------------------------------------
// Fused kernel: block = (batch, 16-row chunk), 512 thr = 8 waves, 1024 blocks.
// R16: swapped MFMA operands (row lane-local); hi-only MFMA; top-4/wave +
//      exact 16th-of-32 threshold (wave-0 computes).
// R17: u32 incremental tile offsets + depth-2 prefetch (named A/B buffers).
// R21 (this round): XCD-AWARE BATCH PINNING — b = blockIdx&7, chunk =
//      blockIdx>>3.  Old mapping (b = blockIdx>>7) spread every batch over
//      all 8 XCDs: each XCD's 4MiB L2 had to hold all 8 batches' working
//      sets (~27MB) -> thrash (FETCH 17.5MB = 4.4x unique data, scans
//      stalling on L3-latency misses that depth-2 prefetch can't cover;
//      explains why R4/R7 issue-side fixes nulled).  New mapping pins batch
//      b's 128 blocks to XCD b (blockIdx%8==b -> HW round-robin): per-XCD
//      working set = one batch ~3.3MB < 4MiB -> L2-resident scans.
//      (s_sleep stagger removed: measured null in R7.)
// Exact rescue (bit-exact fp32 chain) + parallel rank-select + gather.
// ---------------------------------------------------------------------------
__global__ __launch_bounds__(512) void fused_topk_kernel(
    const float* __restrict__ feats,
    const u16*   __restrict__ fhi,
    const float* __restrict__ raw,
    float*       __restrict__ out)
{
    __shared__ union {
        f32x4 vk4[NWV * 16];          // 2 KiB: per-wave top-4 lists [w][row16]
        u64   ckey[RPB * CBS];        // 18.1 KiB: survivors (disjoint in time)
    } sh;
    __shared__ float thr_s[RPB];
    __shared__ int   cnt[RPB];
    __shared__ int   sel[RPB][KTOP];

    const int tid  = threadIdx.x;
    const int lane = tid & 63;
    const int w    = __builtin_amdgcn_readfirstlane(tid >> 6);  // 0..7
    const int b     = (int)(blockIdx.x & 7);     // batch -> XCD b (R21)
    const int chunk = (int)(blockIdx.x >> 3);    // 0..127
    const int rb    = chunk * RPB;           // row base within batch
    const int p     = lane & 15;             // our row (C-col with swapped ops)
    const int q     = lane >> 4;             // cand quad (C-row group)

    if (tid < RPB) cnt[tid] = 0;

    // row fragment (B-operand under swap): rows rb+p, k = q*8..q*8+7
    short8 arow;
    {
        const u32 ae = (u32)((b * NPTS + rb + p) * KPAD + q * 8);
        arow = *(const short8*)(fhi + ae);
    }

    // ---- Pass 1: wave w scans cands [w*128, +128) (8 tiles), running top-4
    //      per (row p, cand-slice q); 2 interleaved lists + depth-2 prefetch.
    float ta0 = -3.0f, ta1 = -3.0f, ta2 = -3.0f, ta3 = -3.0f;
    float tb0 = -3.0f, tb1 = -3.0f, tb2 = -3.0f, tb3 = -3.0f;
    {
        const u32 base1 = (u32)((b * NPTS + w * 128 + p) * KPAD + q * 8);
        short8 pA = *(const short8*)(fhi + base1);          // tile t
        short8 pB = *(const short8*)(fhi + base1 + 512);    // tile t+1
        #pragma unroll
        for (int t = 0; t < 8; t += 2) {
            const short8 c0 = pA;
            if (t + 2 < 8) pA = *(const short8*)(fhi + base1 + (u32)(t + 2) * 512);
            f32x4 acc0 = {0.0f, 0.0f, 0.0f, 0.0f};
            acc0 = __builtin_amdgcn_mfma_f32_16x16x32_bf16(c0, arow, acc0, 0, 0, 0);
            const short8 c1 = pB;
            if (t + 3 < 8) pB = *(const short8*)(fhi + base1 + (u32)(t + 3) * 512);
            f32x4 acc1 = {0.0f, 0.0f, 0.0f, 0.0f};
            acc1 = __builtin_amdgcn_mfma_f32_16x16x32_bf16(c1, arow, acc1, 0, 0, 0);
            #pragma unroll
            for (int i = 0; i < 4; ++i) ins4(ta0, ta1, ta2, ta3, acc0[i]);
            #pragma unroll
            for (int i = 0; i < 4; ++i) ins4(tb0, tb1, tb2, tb3, acc1[i]);
        }
    }
    // merge the two interleaved lists -> top-4 (bitonic: max(a_i, b_{3-i}) + cleanup)
    float t0 = fmaxf(ta0, tb3), t1 = fmaxf(ta1, tb2), t2 = fmaxf(ta2, tb1), t3 = fmaxf(ta3, tb0);
    CE(t0, t2) CE(t1, t3) CE(t0, t1) CE(t2, t3)

    // ---- unify the 4 q-copies of each row (shfl merges) ----
    #pragma unroll
    for (int x = 16; x <= 32; x <<= 1) {
        const float o0 = __shfl_xor(t0, x), o1 = __shfl_xor(t1, x);
        const float o2 = __shfl_xor(t2, x), o3 = __shfl_xor(t3, x);
        float m0 = fmaxf(t0, o3), m1 = fmaxf(t1, o2), m2 = fmaxf(t2, o1), m3 = fmaxf(t3, o0);
        CE(m0, m2) CE(m1, m3) CE(m0, m1) CE(m2, m3)
        t0 = m0; t1 = m1; t2 = m2; t3 = m3;
    }

    // ---- publish per-wave top-4 per row ----
    if (q == 0) {
        f32x4 v4 = {t0, t1, t2, t3};
        sh.vk4[w * 16 + p] = v4;
    }
    __syncthreads();

    // ---- wave 0: exact 16th of the 32 collected values per row ----
    if (w == 0) {
        const int j = q;                       // 0..3
        const f32x4 A  = sh.vk4[j * 16 + p];
        const f32x4 Bv = sh.vk4[(j + 4) * 16 + p];
        // merge two sorted-4 desc -> sorted-8 desc
        float s0 = fmaxf(A[0], Bv[3]), s1 = fmaxf(A[1], Bv[2]);
        float s2 = fmaxf(A[2], Bv[1]), s3 = fmaxf(A[3], Bv[0]);
        float s4 = fminf(A[0], Bv[3]), s5 = fminf(A[1], Bv[2]);
        float s6 = fminf(A[2], Bv[1]), s7 = fminf(A[3], Bv[0]);
        CE(s0, s2) CE(s1, s3) CE(s0, s1) CE(s2, s3)
        CE(s4, s6) CE(s5, s7) CE(s4, s5) CE(s6, s7)
        float s[8] = {s0, s1, s2, s3, s4, s5, s6, s7};
        // j ^ 1 merge: two sorted-8 -> sorted-16 desc
        float t16[16];
        {
            float o[8];
            #pragma unroll
            for (int i = 0; i < 8; ++i) o[i] = __shfl_xor(s[i], 16);
            #pragma unroll
            for (int i = 0; i < 8; ++i) {
                t16[i]     = fmaxf(s[i], o[7 - i]);
                t16[8 + i] = fminf(s[i], o[7 - i]);
            }
            #pragma unroll
            for (int base = 0; base < 16; base += 8) {
                CE(t16[base + 0], t16[base + 4]) CE(t16[base + 1], t16[base + 5])
                CE(t16[base + 2], t16[base + 6]) CE(t16[base + 3], t16[base + 7])
                CE(t16[base + 0], t16[base + 2]) CE(t16[base + 1], t16[base + 3])
                CE(t16[base + 4], t16[base + 6]) CE(t16[base + 5], t16[base + 7])
                CE(t16[base + 0], t16[base + 1]) CE(t16[base + 2], t16[base + 3])
                CE(t16[base + 4], t16[base + 5]) CE(t16[base + 6], t16[base + 7])
            }
        }
        // j ^ 2 final: 16th of union = min_i max(mine[i], other[15-i])
        float z[16];
        #pragma unroll
        for (int i = 0; i < 16; ++i)
            z[i] = fmaxf(t16[i], __shfl_xor(t16[15 - i], 32));
        float mn = z[0];
        #pragma unroll
        for (int i = 1; i < 16; ++i) mn = fminf(mn, z[i]);
        if (q == 0) thr_s[p] = mn - MARGIN;    // lb - 2*eps
    }
    __syncthreads();                 // thr ready; vk4 dead -> ckey usable

    const float thrp = thr_s[p];     // this lane's row threshold

    // ---- Pass 2: all 2048 cands (wave w: [w*256,+256)), depth-2 prefetch ----
    {
        const u32 base2 = (u32)((b * NPTS + w * 256 + p) * KPAD + q * 8);
        short8 pA = *(const short8*)(fhi + base2);
        short8 pB = *(const short8*)(fhi + base2 + 512);
        #pragma unroll
        for (int t = 0; t < 16; t += 2) {
            const short8 c0 = pA;
            if (t + 2 < 16) pA = *(const short8*)(fhi + base2 + (u32)(t + 2) * 512);
            f32x4 acc0 = {0.0f, 0.0f, 0.0f, 0.0f};
            acc0 = __builtin_amdgcn_mfma_f32_16x16x32_bf16(c0, arow, acc0, 0, 0, 0);
            const short8 c1 = pB;
            if (t + 3 < 16) pB = *(const short8*)(fhi + base2 + (u32)(t + 3) * 512);
            f32x4 acc1 = {0.0f, 0.0f, 0.0f, 0.0f};
            acc1 = __builtin_amdgcn_mfma_f32_16x16x32_bf16(c1, arow, acc1, 0, 0, 0);
            const int cb0 = w * 256 + t * 16;
            // early-out: skip the 4 compare-branches when no value hits
            const float mx0 = fmaxf(fmaxf(acc0[0], acc0[1]), fmaxf(acc0[2], acc0[3]));
            if (mx0 >= thrp) {
                #pragma unroll
                for (int i = 0; i < 4; ++i) {
                    if (acc0[i] >= thrp) {
                        const int pos = atomicAdd(&cnt[p], 1);
                        if (pos < CBUF)
                            sh.ckey[p * CBS + pos] = (u64)(u32)(cb0 + q * 4 + i);
                    }
                }
            }
            const float mx1 = fmaxf(fmaxf(acc1[0], acc1[1]), fmaxf(acc1[2], acc1[3]));
            if (mx1 >= thrp) {
                #pragma unroll
                for (int i = 0; i < 4; ++i) {
                    if (acc1[i] >= thrp) {
                        const int pos = atomicAdd(&cnt[p], 1);
                        if (pos < CBUF)
                            sh.ckey[p * CBS + pos] = (u64)(u32)(cb0 + 16 + q * 4 + i);
                    }
                }
            }
        }
    }
    __syncthreads();

    // ---- exact rescue: bit-exact fp32 chain on survivors only ----
    {
        const int r = tid & 15;                  // row within chunk
        const float* fr = feats + (u32)((b * NPTS + rb + r) * DIM);
        float rfn[DIM];
        #pragma unroll
        for (int j = 0; j < 6; ++j)
            *(f32x4*)(rfn + 4 * j) = *(const f32x4*)(fr + 4 * j);
        const int e = (cnt[r] < CBUF) ? cnt[r] : CBUF;
        for (int pos = tid >> 4; pos < e; pos += 32) {
            const int idx = (int)(u32)sh.ckey[r * CBS + pos];
            const float* cp = feats + (u32)((b * NPTS + idx) * DIM);
            float cv[DIM];
            #pragma unroll
            for (int j = 0; j < 6; ++j)
                *(f32x4*)(cv + 4 * j) = *(const f32x4*)(cp + 4 * j);
            float acc = 0.0f;
            #pragma unroll
            for (int d = 0; d < DIM; ++d)
                acc = __builtin_fmaf(cv[d], rfn[d], acc);   // exact chain
            sh.ckey[r * CBS + pos] = ((u64)ordf(acc) << 32) | (u32)(2047 - idx);
        }
    }
    __syncthreads();

    // ---- parallel rank-select: 32 threads per row ----
    {
        const int L = tid >> 5;                  // 0..15
        const int g = tid & 31;
        const int e = (cnt[L] < CBUF) ? cnt[L] : CBUF;
        const u64* rowbuf = &sh.ckey[L * CBS];
        for (int pos = g; pos < e; pos += 32) {
            const u64 key = rowbuf[pos];
            int rank = 0;
            for (int p2 = 0; p2 < e; ++p2) rank += (rowbuf[p2] > key);
            if (rank < KTOP) sel[L][rank] = 2047 - (int)(key & 0xFFFFFFFFull);
        }
    }
    __syncthreads();

    // ---- gather: sx_c[b, n, k, c] = raw[(b*2048 + sel)*12 + c] ----
    // div-free row mapping (L = tid>>5, 32 threads/row, 6 elems each)
    {
        const int rg = b * NPTS + rb;
        const int L = tid >> 5;                  // 0..15
        const int g = tid & 31;
        #pragma unroll
        for (int j = 0; j < 6; ++j) {
            const int e3 = g + j * 32;           // 0..191
            const int k = e3 / CCH;
            const int c = e3 - k * CCH;
            out[((size_t)(rg + L) * KTOP + k) * CCH + c] =
                raw[(u32)((b * NPTS + sel[L][k]) * CCH) + c];
        }
    }
}

// ---------------------------------------------------------------------------
extern "C" void kernel_launch(void* const* d_in, const int* in_sizes, int n_in,
                              void* d_out, int out_size, void* d_ws, size_t ws_size,
                              hipStream_t stream)
{
    const float* x_c    = (const float*)d_in[0];
    const int*   flow_p = (const int*)d_in[1];
    float*       out    = (float*)d_out;

    float* feats = (float*)((char*)d_ws + WS_FEATS);
    float* raw   = (float*)((char*)d_ws + WS_RAW);
    u16*   fhi   = (u16*)  ((char*)d_ws + WS_FHI);

    prep_kernel<<<NROWS / 64, 64, 0, stream>>>(x_c, flow_p, feats, fhi, raw, out);
    fused_topk_kernel<<<BS * 128, 512, 0, stream>>>(feats, fhi, raw, out);
}